// Round 11
// baseline (227.872 us; speedup 1.0000x reference)
//
#include <hip/hip_runtime.h>
#include <math.h>

#define S_TOT 16384
#define BATCH 4
#define DIN 512
#define NH 8
#define DK 64
#define SEGF 2048
#define SEGS 512
#define NSEG 8
#define NUSE 2
#define MROWS (BATCH*NUSE*SEGS)   // 4096 rows through attention/MLP

typedef unsigned int u32;
typedef __attribute__((ext_vector_type(8))) short short8;
typedef __attribute__((ext_vector_type(4))) float f32x4;

__device__ __forceinline__ short f2b(float f) {
  u32 u = __float_as_uint(f);
  u32 r = u + 0x7fffu + ((u >> 16) & 1u);
  return (short)(r >> 16);
}
__device__ __forceinline__ float b2f(short s) {
  return __uint_as_float(((u32)(unsigned short)s) << 16);
}

// ---------------- fused: scores (blocks 0..16383) + weight transpose/cast --------
__global__ __launch_bounds__(256) void scores_transpose(
    const float* __restrict__ x, const float* __restrict__ w,
    const float* __restrict__ bsamp, float* __restrict__ out,
    const float* __restrict__ w_q, const float* __restrict__ w_k,
    const float* __restrict__ w_v, const float* __restrict__ w_o,
    const float* __restrict__ w1,  const float* __restrict__ w2,
    short* __restrict__ Wtqkv, short* __restrict__ Wob,
    short* __restrict__ Wt1,   short* __restrict__ Wt2)
{
  __shared__ float t[32][33];
  int tid = threadIdx.x;
  if (blockIdx.x < 16384) {
    int tok  = blockIdx.x * 4 + (tid >> 6);
    int lane = tid & 63;
    const float4* xr = (const float4*)(x + (size_t)tok * DIN);
    const float4* wr = (const float4*)w;
    float4 a0 = xr[lane],      w0 = wr[lane];
    float4 a1 = xr[lane + 64], w1v = wr[lane + 64];
    float p = a0.x*w0.x + a0.y*w0.y + a0.z*w0.z + a0.w*w0.w
            + a1.x*w1v.x + a1.y*w1v.y + a1.z*w1v.z + a1.w*w1v.w;
    #pragma unroll
    for (int off = 32; off > 0; off >>= 1) p += __shfl_down(p, off);
    if (lane == 0) out[tok] = p + bsamp[0];
    return;
  }
  int bid = blockIdx.x - 16384;
  int txx = tid & 31, ty = tid >> 5;
  if (bid >= 768 && bid < 1024) {
    int tIdx = bid - 768;
    int n0 = (tIdx & 15) * 32, k0 = (tIdx >> 4) * 32;
    #pragma unroll
    for (int r = 0; r < 4; ++r) {
      size_t idx = (size_t)(k0 + ty + 8*r) * 512 + n0 + txx;
      Wob[idx] = f2b(w_o[idx]);
    }
    return;
  }
  const float* src; short* dst; int K, N, rowoff, tIdx;
  if (bid < 768) {
    K = 512; N = 512; tIdx = bid & 255;
    int which = bid >> 8;
    src = which == 0 ? w_q : which == 1 ? w_k : w_v;
    dst = Wtqkv;
    rowoff = which * 512;
  } else if (bid < 2048) {
    K = 512; N = 2048; tIdx = bid - 1024; src = w1; dst = Wt1; rowoff = 0;
  } else {
    K = 2048; N = 512; tIdx = bid - 2048; src = w2; dst = Wt2; rowoff = 0;
  }
  int ntN = N >> 5;
  int n0 = (tIdx % ntN) * 32, k0 = (tIdx / ntN) * 32;
  #pragma unroll
  for (int r = 0; r < 4; ++r)
    t[ty + 8*r][txx] = src[(size_t)(k0 + ty + 8*r) * N + n0 + txx];
  __syncthreads();
  #pragma unroll
  for (int r = 0; r < 4; ++r)
    dst[(size_t)(rowoff + n0 + ty + 8*r) * K + k0 + txx] = f2b(t[txx][ty + 8*r]);
}

// ---------------- topk pass 1: stable rank, 1024 thr, 4-way scan split ----------
__global__ __launch_bounds__(1024) void topk_rank(
    const float* __restrict__ scores, int* __restrict__ flags,
    float* __restrict__ maskOut)
{
  int c = blockIdx.x & 7, g = (blockIdx.x >> 3) & 7, b = blockIdx.x >> 6;
  __shared__ float sc[SEGF];
  __shared__ int pcnt[3][256];
  int tid = threadIdx.x;
  const float* src = scores + (size_t)b*S_TOT + (size_t)g*SEGF;
  *(float2*)&sc[tid*2] = *(const float2*)(src + tid*2);
  __syncthreads();
  int e = tid & 255;
  int q = tid >> 8;
  int i0 = c*256 + e;
  float mine = sc[i0];
  int cnt = 0;
  int j0 = q * 512;
  #pragma unroll 2
  for (int j = j0; j < j0 + 512; j += 8) {
    float4 a = *(const float4*)&sc[j];
    float4 d = *(const float4*)&sc[j + 4];
    cnt += (a.x > mine || (a.x == mine && (j+0) < i0)) ? 1 : 0;
    cnt += (a.y > mine || (a.y == mine && (j+1) < i0)) ? 1 : 0;
    cnt += (a.z > mine || (a.z == mine && (j+2) < i0)) ? 1 : 0;
    cnt += (a.w > mine || (a.w == mine && (j+3) < i0)) ? 1 : 0;
    cnt += (d.x > mine || (d.x == mine && (j+4) < i0)) ? 1 : 0;
    cnt += (d.y > mine || (d.y == mine && (j+5) < i0)) ? 1 : 0;
    cnt += (d.z > mine || (d.z == mine && (j+6) < i0)) ? 1 : 0;
    cnt += (d.w > mine || (d.w == mine && (j+7) < i0)) ? 1 : 0;
  }
  if (q) pcnt[q-1][e] = cnt;
  __syncthreads();
  if (q == 0) {
    cnt += pcnt[0][e] + pcnt[1][e] + pcnt[2][e];
    int flg = (cnt < SEGS) ? 1 : 0;
    flags[(((b << 3) + g) << 11) + i0] = flg;
    maskOut[(size_t)b*S_TOT + (size_t)g*SEGF + i0] = flg ? 1.0f : 0.0f;
  }
}

// ---------------- topk pass 2: compact selected indices (g<NUSE) ----------------
__global__ __launch_bounds__(256) void topk_compact(
    const int* __restrict__ flags, int* __restrict__ flat, int* __restrict__ inv)
{
  int g = blockIdx.x & 1, b = blockIdx.x >> 1;
  __shared__ int wsum[4];
  int tid = threadIdx.x;
  int lane = tid & 63, w = tid >> 6;
  const int* f = flags + (((b << 3) + g) << 11);
  int fl[8]; int ls = 0;
  #pragma unroll
  for (int l = 0; l < 8; ++l) { fl[l] = f[tid*8 + l]; ls += fl[l]; }
  int inc = ls;
  #pragma unroll
  for (int off = 1; off < 64; off <<= 1) {
    int t = __shfl_up(inc, off);
    if (lane >= off) inc += t;
  }
  if (lane == 63) wsum[w] = inc;
  __syncthreads();
  int base = 0;
  #pragma unroll
  for (int ww = 0; ww < 4; ++ww) base += (ww < w) ? wsum[ww] : 0;
  int pos = base + inc - ls;
  #pragma unroll
  for (int l = 0; l < 8; ++l) {
    int i = tid*8 + l;
    inv[b*(NUSE*SEGF) + g*SEGF + i] = fl[l] ? (g*SEGS + pos) : -1;
    if (fl[l]) {
      flat[b*(NSEG*SEGS) + g*SEGS + pos] = g*SEGF + i;
      pos++;
    }
  }
}

// ---------------- gather (blocks <1024) + base output write (rest) ----------------
__global__ __launch_bounds__(256) void gather_base(
    const float* __restrict__ x, const int* __restrict__ flat,
    const int* __restrict__ inv, short* __restrict__ xsel,
    float* __restrict__ outX)
{
  int tid = threadIdx.x;
  int lane = tid & 63;
  if (blockIdx.x < 1024) {
    int tok = blockIdx.x * 4 + (tid >> 6);
    int b = tok >> 10, i = tok & 1023;
    int gidx = flat[b * (NSEG*SEGS) + i];
    const float* srcp = x + ((size_t)(b * S_TOT + gidx)) * DIN + lane*8;
    float4 a0 = *(const float4*)srcp;
    float4 a1 = *(const float4*)(srcp + 4);
    uint4 o;
    o.x = (u32)(unsigned short)f2b(a0.x) | ((u32)(unsigned short)f2b(a0.y) << 16);
    o.y = (u32)(unsigned short)f2b(a0.z) | ((u32)(unsigned short)f2b(a0.w) << 16);
    o.z = (u32)(unsigned short)f2b(a1.x) | ((u32)(unsigned short)f2b(a1.y) << 16);
    o.w = (u32)(unsigned short)f2b(a1.z) | ((u32)(unsigned short)f2b(a1.w) << 16);
    *(uint4*)(xsel + (size_t)tok * DIN + lane*8) = o;
    return;
  }
  int row = (blockIdx.x - 1024) * 4 + (tid >> 6);
  int b = row >> 14;
  int s = row & (S_TOT - 1);
  size_t base = (size_t)row * DIN + lane * 8;
  if (s >= NUSE * SEGF) {
    float4 z = make_float4(0.f,0.f,0.f,0.f);
    *(float4*)(outX + base)     = z;
    *(float4*)(outX + base + 4) = z;
    return;
  }
  if (inv[b * (NUSE*SEGF) + s] >= 0) return;   // MLP2 scatter writes these
  *(float4*)(outX + base)     = *(const float4*)(x + base);
  *(float4*)(outX + base + 4) = *(const float4*)(x + base + 4);
}

// ---------------- bf16 MFMA GEMM, 2-phase pipeline, templated BK --------------
// If xres != nullptr: scatter epilogue — outCf[b][flat[r]][c] = xres[..] + v.
template<int BM, int BN, int WM, int WN, int BK>
__global__ __launch_bounds__(256) void gemm_bf16(
    const short* __restrict__ A, const short* __restrict__ Bt,
    const float* __restrict__ bias, float* __restrict__ Cf,
    short* __restrict__ Cb, short* __restrict__ VtOut, short* __restrict__ KtOut,
    const float* __restrict__ xres, const int* __restrict__ gflat,
    int M, int N, int K, int act)
{
  constexpr int WAVES_N = BN / WN;
  constexpr int FM = WM / 16, FN = WN / 16;
  constexpr int RPB = BK / 8;
  __shared__ short Al[2][BM * BK];
  __shared__ short Bl[2][BN * BK];
  const int tid = threadIdx.x;
  const int lane = tid & 63, wid = tid >> 6;
  const int wr = wid / WAVES_N, wc = wid % WAVES_N;
  const int bm = blockIdx.y * BM, bn = blockIdx.x * BN;
  const int ln15 = lane & 15, hi8 = (lane >> 4) * 8;

  f32x4 acc[FM][FN];
  #pragma unroll
  for (int i = 0; i < FM; ++i)
    #pragma unroll
    for (int j = 0; j < FN; ++j)
      #pragma unroll
      for (int e = 0; e < 4; ++e) acc[i][j][e] = 0.f;

  const int NT = K / BK;

  auto stage = [&](int t, int buf) {
    const int k0 = t * BK;
    #pragma unroll
    for (int i = 0; i < BM*BK/2048; ++i) {
      int slot = i*256 + tid;
      int row = slot / RPB, col = (slot % RPB) * 8;
      const short* gp = A + (size_t)(bm + row) * K + k0 + col;
      __builtin_amdgcn_global_load_lds(
          (const __attribute__((address_space(1))) void*)gp,
          (__attribute__((address_space(3))) void*)&Al[buf][row*BK + col],
          16, 0, 0);
    }
    #pragma unroll
    for (int i = 0; i < BN*BK/2048; ++i) {
      int slot = i*256 + tid;
      int row = slot / RPB, col = (slot % RPB) * 8;
      const short* gp = Bt + (size_t)(bn + row) * K + k0 + col;
      __builtin_amdgcn_global_load_lds(
          (const __attribute__((address_space(1))) void*)gp,
          (__attribute__((address_space(3))) void*)&Bl[buf][row*BK + col],
          16, 0, 0);
    }
  };

  stage(0, 0);
  __syncthreads();
  int cur = 0;
  for (int t = 0; t < NT; ++t) {
    if (t + 1 < NT) stage(t + 1, cur ^ 1);
    #pragma unroll
    for (int ks = 0; ks < BK/32; ++ks) {
      short8 af[FM], bf_[FN];
      #pragma unroll
      for (int fm = 0; fm < FM; ++fm)
        af[fm] = *(const short8*)&Al[cur][(wr*WM + fm*16 + ln15)*BK + ks*32 + hi8];
      #pragma unroll
      for (int fn = 0; fn < FN; ++fn)
        bf_[fn] = *(const short8*)&Bl[cur][(wc*WN + fn*16 + ln15)*BK + ks*32 + hi8];
      #pragma unroll
      for (int fm = 0; fm < FM; ++fm)
        #pragma unroll
        for (int fn = 0; fn < FN; ++fn)
          acc[fm][fn] = __builtin_amdgcn_mfma_f32_16x16x32_bf16(af[fm], bf_[fn], acc[fm][fn], 0, 0, 0);
    }
    __syncthreads();
    cur ^= 1;
  }

  const int crow0 = (lane >> 4) * 4, ccol = lane & 15;
  #pragma unroll
  for (int fm = 0; fm < FM; ++fm) {
    int r0 = bm + wr*WM + fm*16 + crow0;
    int toks[4];
    if (xres) {
      int bb2 = r0 >> 10;
      #pragma unroll
      for (int j = 0; j < 4; ++j)
        toks[j] = bb2 * S_TOT + gflat[bb2 * (NSEG*SEGS) + ((r0 + j) & 1023)];
    }
    #pragma unroll
    for (int fn = 0; fn < FN; ++fn) {
      int c = bn + wc*WN + fn*16 + ccol;
      float vv[4];
      #pragma unroll
      for (int j = 0; j < 4; ++j) {
        float v = acc[fm][fn][j];
        if (bias) v += bias[c];
        if (act == 1) v = 0.5f * v * (1.0f + erff(v * 0.70710678118f));
        vv[j] = v;
        if (xres) {
          size_t o = (size_t)toks[j] * DIN + c;
          Cf[o] = xres[o] + v;
        } else {
          if (Cf) Cf[(size_t)(r0 + j) * N + c] = v;
          if (Cb) Cb[(size_t)(r0 + j) * N + c] = f2b(v);
        }
      }
      if (VtOut && c >= 1024) {
        int hh = (c - 1024) >> 6, dv = c & 63;
        int bb = r0 >> 10, key = r0 & 1023;
        u32 lo = (u32)(unsigned short)f2b(vv[0]) | ((u32)(unsigned short)f2b(vv[1]) << 16);
        u32 hi = (u32)(unsigned short)f2b(vv[2]) | ((u32)(unsigned short)f2b(vv[3]) << 16);
        *(uint2*)&VtOut[((size_t)((bb*8 + hh)*64 + dv) << 10) + key] = make_uint2(lo, hi);
      }
      if (KtOut && c >= 512 && c < 1024) {
        int hh = (c - 512) >> 6, dk = c & 63;
        int bb = r0 >> 10, key = r0 & 1023;
        float e0 = vv[0] > 0.f ? vv[0] + 1.f : __expf(vv[0]);
        float e1 = vv[1] > 0.f ? vv[1] + 1.f : __expf(vv[1]);
        float e2 = vv[2] > 0.f ? vv[2] + 1.f : __expf(vv[2]);
        float e3 = vv[3] > 0.f ? vv[3] + 1.f : __expf(vv[3]);
        u32 lo = (u32)(unsigned short)f2b(e0) | ((u32)(unsigned short)f2b(e1) << 16);
        u32 hi = (u32)(unsigned short)f2b(e2) | ((u32)(unsigned short)f2b(e3) << 16);
        *(uint2*)&KtOut[((size_t)((bb*8 + hh)*64 + dk) << 10) + key] = make_uint2(lo, hi);
      }
    }
  }
}

// ---------------- fused MFMA attention + inline memsum (g=1) ----------
__global__ __launch_bounds__(256) void attn4(
    const short* __restrict__ qkv, const short* __restrict__ vt,
    const short* __restrict__ kt, const float* __restrict__ betas,
    short* __restrict__ att)
{
  __shared__ short Ks[128*64];      // [key][dk]; reused for Mt
  __shared__ short Vts[64*128];     // [dv][key]
  __shared__ short Ps[4*16*128];    // per-wave P
  __shared__ float zl[64];
  __shared__ float relay[64];
  int tid = threadIdx.x, lane = tid & 63, w = tid >> 6;
  int ln15 = lane & 15, hi8 = (lane >> 4) * 8;
  int bx = blockIdx.x;
  int qt = bx & 7, h = (bx >> 3) & 7, g = (bx >> 6) & 1, b = bx >> 7;
  const int seg0 = b*1024 + g*512;
  const int qbase = seg0 + qt*64;

  short8 qf[2];
  {
    const short* qg = qkv + (size_t)(qbase + w*16 + ln15)*1536 + h*64;
    qf[0] = *(const short8*)(qg + hi8);
    qf[1] = *(const short8*)(qg + 32 + hi8);
  }

  const short* ktb = kt + ((size_t)((b*8+h)*64) << 10);   // seg0 keys 0..511
  const short* vtb = vt + ((size_t)((b*8+h)*64) << 10);
  // inline z = rowsum(Kt seg0) for g=1
  if (g) {
    int zrow = tid >> 2, zq = tid & 3;
    float zs = 0.f;
    #pragma unroll 4
    for (int i = 0; i < 16; ++i) {
      short8 kv = *(const short8*)&ktb[(size_t)zrow*1024 + zq*128 + i*8];
      #pragma unroll
      for (int e2 = 0; e2 < 8; ++e2) zs += b2f(kv[e2]);
    }
    zs += __shfl_xor(zs, 1); zs += __shfl_xor(zs, 2);
    if (zq == 0) zl[zrow] = 0.015625f + zs;
  }

  const short* kg = qkv + (size_t)seg0*1536 + 512 + h*64;
  const short* vg = vtb + g*512;
  short* Pw = &Ps[w*2048];

  f32x4 oacc[4];
  #pragma unroll
  for (int nf = 0; nf < 4; ++nf) oacc[nf] = (f32x4){0.f,0.f,0.f,0.f};
  float lsum[4] = {0.f,0.f,0.f,0.f};

  for (int c = 0; c < 4; ++c) {
    __syncthreads();
    #pragma unroll
    for (int p = 0; p < 4; ++p) {
      int slot = p*256 + tid;
      int row = slot >> 3;
      int off = ((slot & 7)*8) ^ ((row & 7)*8);
      __builtin_amdgcn_global_load_lds(
        (const __attribute__((address_space(1))) void*)(kg + (size_t)(c*128 + row)*1536 + off),
        (__attribute__((address_space(3))) void*)&Ks[slot*8], 16, 0, 0);
    }
    #pragma unroll
    for (int p = 0; p < 4; ++p) {
      int slot = p*256 + tid;
      int row = slot >> 4;
      int off = ((slot & 15)*8) ^ ((row & 7)*8);
      __builtin_amdgcn_global_load_lds(
        (const __attribute__((address_space(1))) void*)(vg + ((size_t)row << 10) + c*128 + off),
        (__attribute__((address_space(3))) void*)&Vts[slot*8], 16, 0, 0);
    }
    __syncthreads();

    f32x4 sf[8];
    #pragma unroll
    for (int nf = 0; nf < 8; ++nf) sf[nf] = (f32x4){0.f,0.f,0.f,0.f};
    __builtin_amdgcn_s_setprio(1);
    #pragma unroll
    for (int ks = 0; ks < 2; ++ks)
      #pragma unroll
      for (int nf = 0; nf < 8; ++nf) {
        int row = nf*16 + ln15;
        short8 kb = *(const short8*)&Ks[row*64 + ((ks*32 + hi8) ^ ((row&7)*8))];
        sf[nf] = __builtin_amdgcn_mfma_f32_16x16x32_bf16(qf[ks], kb, sf[nf], 0, 0, 0);
      }
    __builtin_amdgcn_s_setprio(0);
    #pragma unroll
    for (int nf = 0; nf < 8; ++nf)
      #pragma unroll
      for (int j = 0; j < 4; ++j) {
        float p = __expf(sf[nf][j] * 0.125f);
        lsum[j] += p;
        int q = (lane >> 4)*4 + j;
        int key = nf*16 + ln15;
        Pw[q*128 + (key ^ ((q&7)*8))] = f2b(p);
      }
    __builtin_amdgcn_s_setprio(1);
    #pragma unroll
    for (int ks = 0; ks < 4; ++ks) {
      short8 pa = *(const short8*)&Pw[ln15*128 + ((ks*32 + hi8) ^ ((ln15&7)*8))];
      #pragma unroll
      for (int nf = 0; nf < 4; ++nf) {
        int row = nf*16 + ln15;
        short8 vb = *(const short8*)&Vts[row*128 + ((ks*32 + hi8) ^ ((row&7)*8))];
        oacc[nf] = __builtin_amdgcn_mfma_f32_16x16x32_bf16(pa, vb, oacc[nf], 0, 0, 0);
      }
    }
    __builtin_amdgcn_s_setprio(0);
  }

  float linv[4];
  #pragma unroll
  for (int j = 0; j < 4; ++j) {
    float s = lsum[j];
    s += __shfl_xor(s, 1); s += __shfl_xor(s, 2);
    s += __shfl_xor(s, 4); s += __shfl_xor(s, 8);
    linv[j] = 1.f / s;
  }

  f32x4 mfr[4];
  #pragma unroll
  for (int nf = 0; nf < 4; ++nf) mfr[nf] = (f32x4){0.f,0.f,0.f,0.f};
  float dinv[4] = {0.f,0.f,0.f,0.f};
  if (g) {
    __syncthreads();   // all waves done with Ks
    // compute Mt = Vt(seg0) @ Kt(seg0)^T via MFMA, store bf16 swizzled into Ks
    f32x4 macc[4];
    #pragma unroll
    for (int nf = 0; nf < 4; ++nf) macc[nf] = (f32x4){0.f,0.f,0.f,0.f};
    #pragma unroll 4
    for (int ks = 0; ks < 16; ++ks) {
      short8 a = *(const short8*)&vtb[(size_t)(w*16 + ln15)*1024 + ks*32 + hi8];
      #pragma unroll
      for (int nf = 0; nf < 4; ++nf) {
        short8 bb = *(const short8*)&ktb[(size_t)(nf*16 + ln15)*1024 + ks*32 + hi8];
        macc[nf] = __builtin_amdgcn_mfma_f32_16x16x32_bf16(a, bb, macc[nf], 0, 0, 0);
      }
    }
    #pragma unroll
    for (int nf = 0; nf < 4; ++nf)
      #pragma unroll
      for (int j = 0; j < 4; ++j) {
        int dvr = w*16 + (lane>>4)*4 + j;
        int dkc = nf*16 + ln15;
        Ks[dvr*64 + (dkc ^ ((dvr&7)*8))] = f2b(macc[nf][j]);
      }
    __syncthreads();
    float sqv[2][8]; short8 sqf[2];
    #pragma unroll
    for (int ks = 0; ks < 2; ++ks)
      #pragma unroll
      for (int e = 0; e < 8; ++e) {
        float f = b2f(qf[ks][e]);
        f = f > 0.f ? f + 1.f : __expf(f);
        sqv[ks][e] = f; sqf[ks][e] = f2b(f);
      }
    float denp = 0.f;
    #pragma unroll
    for (int ks = 0; ks < 2; ++ks)
      #pragma unroll
      for (int e = 0; e < 8; ++e) denp += sqv[ks][e] * zl[ks*32 + hi8 + e];
    denp += __shfl_xor(denp, 16); denp += __shfl_xor(denp, 32);
    if (lane < 16) relay[w*16 + lane] = denp;
    #pragma unroll
    for (int ks = 0; ks < 2; ++ks)
      #pragma unroll
      for (int nf = 0; nf < 4; ++nf) {
        int row = nf*16 + ln15;
        short8 mb_ = *(const short8*)&Ks[row*64 + ((ks*32 + hi8) ^ ((row&7)*8))];
        mfr[nf] = __builtin_amdgcn_mfma_f32_16x16x32_bf16(sqf[ks], mb_, mfr[nf], 0, 0, 0);
      }
    #pragma unroll
    for (int j = 0; j < 4; ++j)
      dinv[j] = 1.f / relay[w*16 + (lane>>4)*4 + j];
  }

  #pragma unroll
  for (int nf = 0; nf < 4; ++nf) {
    float bt = betas[h*64 + nf*16 + ln15];
    float gt = 1.f / (1.f + __expf(-bt));
    #pragma unroll
    for (int j = 0; j < 4; ++j) {
      float ad = oacc[nf][j] * linv[j];
      float v = g ? (gt * mfr[nf][j] * dinv[j] + (1.f - gt) * ad) : (1.f - gt) * ad;
      int qrow = qbase + w*16 + (lane>>4)*4 + j;
      att[(size_t)qrow*512 + h*64 + nf*16 + ln15] = f2b(v);
    }
  }
}

extern "C" void kernel_launch(void* const* d_in, const int* in_sizes, int n_in,
                              void* d_out, int out_size, void* d_ws, size_t ws_size,
                              hipStream_t stream) {
  (void)in_sizes; (void)n_in; (void)out_size; (void)ws_size;
  const float* x      = (const float*)d_in[0];
  const float* w_samp = (const float*)d_in[1];
  const float* b_samp = (const float*)d_in[2];
  const float* w_q    = (const float*)d_in[3];
  const float* w_k    = (const float*)d_in[4];
  const float* w_v    = (const float*)d_in[5];
  const float* w_o    = (const float*)d_in[6];
  const float* betas  = (const float*)d_in[7];
  const float* w1     = (const float*)d_in[8];
  const float* b1     = (const float*)d_in[9];
  const float* w2     = (const float*)d_in[10];
  const float* b2     = (const float*)d_in[11];

  float* outX      = (float*)d_out;
  float* outMask   = outX + (size_t)BATCH * S_TOT * DIN;
  float* outScores = outMask + (size_t)BATCH * S_TOT;

  char* ws = (char*)d_ws;
  int*   flat  = (int*)(ws);                    // 64 KB
  int*   inv   = (int*)(ws + 65536);            // 64 KB
  int*   flags = (int*)(ws + 131072);           // 256 KB
  short* Wtqkv = (short*)(ws + 1048576);        // [1536][512] bf16, 1.5 MB
  short* Wob   = (short*)(ws + 2621440);        // [512][512] plain cast, 0.5 MB
  short* Wt1   = (short*)(ws + 3145728);        // [2048][512], 2 MB
  short* Wt2   = (short*)(ws + 5242880);        // [512][2048], 2 MB
  short* xsel  = (short*)(ws + 7340032);        // [4096][512], 4 MB
  short* qkv   = (short*)(ws + 11534336);       // [4096][1536], 12 MB
  short* Vt    = (short*)(ws + 24117248);       // [4][8][64][1024], 4 MB
  short* attb  = (short*)(ws + 28311552);       // [4096][512], 4 MB
  short* Kt    = (short*)(ws + 36700160);       // [4][8][64][1024], 4 MB
  short* WfT   = (short*)(ws + 40894464);       // [2048][512] = (w_o@w1)^T, 2 MB
  short* hidB  = (short*)(ws + 7340032);        // [4096][2048] overlays xsel+qkv

  scores_transpose<<<16384 + 3072, 256, 0, stream>>>(
      x, w_samp, b_samp, outScores,
      w_q, w_k, w_v, w_o, w1, w2, Wtqkv, Wob, Wt1, Wt2);
  topk_rank<<<BATCH*NSEG*8, 1024, 0, stream>>>(outScores, flags, outMask);
  topk_compact<<<BATCH*NUSE, 256, 0, stream>>>(flags, flat, inv);

  gemm_bf16<64,64,32,32,64><<<dim3(8,32), 256, 0, stream>>>(
      Wt1, Wob, nullptr, nullptr, WfT, nullptr, nullptr, nullptr, nullptr,
      2048, 512, 512, 0);

  gather_base<<<1024 + 16384, 256, 0, stream>>>(x, flat, inv, xsel, outX);

  gemm_bf16<128,128,64,64,32><<<dim3(12,32), 256, 0, stream>>>(
      xsel, Wtqkv, nullptr, nullptr, qkv, Vt, Kt, nullptr, nullptr,
      MROWS, 1536, 512, 0);

  attn4<<<512, 256, 0, stream>>>(qkv, Vt, Kt, betas, attb);

  gemm_bf16<128,128,64,64,32><<<dim3(16,32), 256, 0, stream>>>(
      attb, WfT, b1, nullptr, hidB, nullptr, nullptr, nullptr, nullptr,
      MROWS, 2048, 512, 1);
  // MLP2 + scatter: outX[b][flat[r]][:] = x[...] + (hid @ w2 + b2)
  gemm_bf16<64,64,32,32,64><<<dim3(8,64), 256, 0, stream>>>(
      hidB, Wt2, b2, outX, nullptr, nullptr, nullptr, x, flat,
      MROWS, 512, 2048, 0);
}

// Round 12
// 215.015 us; speedup vs baseline: 1.0598x; 1.0598x over previous
//
#include <hip/hip_runtime.h>
#include <math.h>

#define S_TOT 16384
#define BATCH 4
#define DIN 512
#define NH 8
#define DK 64
#define SEGF 2048
#define SEGS 512
#define NSEG 8
#define NUSE 2
#define MROWS (BATCH*NUSE*SEGS)   // 4096 rows through attention/MLP

typedef unsigned int u32;
typedef __attribute__((ext_vector_type(8))) short short8;
typedef __attribute__((ext_vector_type(4))) float f32x4;

__device__ __forceinline__ short f2b(float f) {
  u32 u = __float_as_uint(f);
  u32 r = u + 0x7fffu + ((u >> 16) & 1u);
  return (short)(r >> 16);
}
__device__ __forceinline__ float b2f(short s) {
  return __uint_as_float(((u32)(unsigned short)s) << 16);
}

// ---------------- fused: scores (blocks 0..16383) + weight transpose/cast --------
__global__ __launch_bounds__(256) void scores_transpose(
    const float* __restrict__ x, const float* __restrict__ w,
    const float* __restrict__ bsamp, float* __restrict__ out,
    const float* __restrict__ w_q, const float* __restrict__ w_k,
    const float* __restrict__ w_v, const float* __restrict__ w_o,
    const float* __restrict__ w1,  const float* __restrict__ w2,
    short* __restrict__ Wtqkv, short* __restrict__ Wob,
    short* __restrict__ Wt1,   short* __restrict__ Wt2)
{
  __shared__ float t[32][33];
  int tid = threadIdx.x;
  if (blockIdx.x < 16384) {
    int tok  = blockIdx.x * 4 + (tid >> 6);
    int lane = tid & 63;
    const float4* xr = (const float4*)(x + (size_t)tok * DIN);
    const float4* wr = (const float4*)w;
    float4 a0 = xr[lane],      w0 = wr[lane];
    float4 a1 = xr[lane + 64], w1v = wr[lane + 64];
    float p = a0.x*w0.x + a0.y*w0.y + a0.z*w0.z + a0.w*w0.w
            + a1.x*w1v.x + a1.y*w1v.y + a1.z*w1v.z + a1.w*w1v.w;
    #pragma unroll
    for (int off = 32; off > 0; off >>= 1) p += __shfl_down(p, off);
    if (lane == 0) out[tok] = p + bsamp[0];
    return;
  }
  int bid = blockIdx.x - 16384;
  int txx = tid & 31, ty = tid >> 5;
  if (bid >= 768 && bid < 1024) {
    int tIdx = bid - 768;
    int n0 = (tIdx & 15) * 32, k0 = (tIdx >> 4) * 32;
    #pragma unroll
    for (int r = 0; r < 4; ++r) {
      size_t idx = (size_t)(k0 + ty + 8*r) * 512 + n0 + txx;
      Wob[idx] = f2b(w_o[idx]);
    }
    return;
  }
  const float* src; short* dst; int K, N, rowoff, tIdx;
  if (bid < 768) {
    K = 512; N = 512; tIdx = bid & 255;
    int which = bid >> 8;
    src = which == 0 ? w_q : which == 1 ? w_k : w_v;
    dst = Wtqkv;
    rowoff = which * 512;
  } else if (bid < 2048) {
    K = 512; N = 2048; tIdx = bid - 1024; src = w1; dst = Wt1; rowoff = 0;
  } else {
    K = 2048; N = 512; tIdx = bid - 2048; src = w2; dst = Wt2; rowoff = 0;
  }
  int ntN = N >> 5;
  int n0 = (tIdx % ntN) * 32, k0 = (tIdx / ntN) * 32;
  #pragma unroll
  for (int r = 0; r < 4; ++r)
    t[ty + 8*r][txx] = src[(size_t)(k0 + ty + 8*r) * N + n0 + txx];
  __syncthreads();
  #pragma unroll
  for (int r = 0; r < 4; ++r)
    dst[(size_t)(rowoff + n0 + ty + 8*r) * K + k0 + txx] = f2b(t[txx][ty + 8*r]);
}

// ---------------- topk pass 1: stable rank, 1024 thr, 4-way scan split ----------
__global__ __launch_bounds__(1024) void topk_rank(
    const float* __restrict__ scores, int* __restrict__ flags,
    float* __restrict__ maskOut)
{
  int c = blockIdx.x & 7, g = (blockIdx.x >> 3) & 7, b = blockIdx.x >> 6;
  __shared__ float sc[SEGF];
  __shared__ int pcnt[3][256];
  int tid = threadIdx.x;
  const float* src = scores + (size_t)b*S_TOT + (size_t)g*SEGF;
  *(float2*)&sc[tid*2] = *(const float2*)(src + tid*2);
  __syncthreads();
  int e = tid & 255;
  int q = tid >> 8;
  int i0 = c*256 + e;
  float mine = sc[i0];
  int cnt = 0;
  int j0 = q * 512;
  #pragma unroll 2
  for (int j = j0; j < j0 + 512; j += 8) {
    float4 a = *(const float4*)&sc[j];
    float4 d = *(const float4*)&sc[j + 4];
    cnt += (a.x > mine || (a.x == mine && (j+0) < i0)) ? 1 : 0;
    cnt += (a.y > mine || (a.y == mine && (j+1) < i0)) ? 1 : 0;
    cnt += (a.z > mine || (a.z == mine && (j+2) < i0)) ? 1 : 0;
    cnt += (a.w > mine || (a.w == mine && (j+3) < i0)) ? 1 : 0;
    cnt += (d.x > mine || (d.x == mine && (j+4) < i0)) ? 1 : 0;
    cnt += (d.y > mine || (d.y == mine && (j+5) < i0)) ? 1 : 0;
    cnt += (d.z > mine || (d.z == mine && (j+6) < i0)) ? 1 : 0;
    cnt += (d.w > mine || (d.w == mine && (j+7) < i0)) ? 1 : 0;
  }
  if (q) pcnt[q-1][e] = cnt;
  __syncthreads();
  if (q == 0) {
    cnt += pcnt[0][e] + pcnt[1][e] + pcnt[2][e];
    int flg = (cnt < SEGS) ? 1 : 0;
    flags[(((b << 3) + g) << 11) + i0] = flg;
    maskOut[(size_t)b*S_TOT + (size_t)g*SEGF + i0] = flg ? 1.0f : 0.0f;
  }
}

// ---------------- topk pass 2: compact selected indices (g<NUSE) ----------------
__global__ __launch_bounds__(256) void topk_compact(
    const int* __restrict__ flags, int* __restrict__ flat, int* __restrict__ inv)
{
  int g = blockIdx.x & 1, b = blockIdx.x >> 1;
  __shared__ int wsum[4];
  int tid = threadIdx.x;
  int lane = tid & 63, w = tid >> 6;
  const int* f = flags + (((b << 3) + g) << 11);
  int fl[8]; int ls = 0;
  #pragma unroll
  for (int l = 0; l < 8; ++l) { fl[l] = f[tid*8 + l]; ls += fl[l]; }
  int inc = ls;
  #pragma unroll
  for (int off = 1; off < 64; off <<= 1) {
    int t = __shfl_up(inc, off);
    if (lane >= off) inc += t;
  }
  if (lane == 63) wsum[w] = inc;
  __syncthreads();
  int base = 0;
  #pragma unroll
  for (int ww = 0; ww < 4; ++ww) base += (ww < w) ? wsum[ww] : 0;
  int pos = base + inc - ls;
  #pragma unroll
  for (int l = 0; l < 8; ++l) {
    int i = tid*8 + l;
    inv[b*(NUSE*SEGF) + g*SEGF + i] = fl[l] ? (g*SEGS + pos) : -1;
    if (fl[l]) {
      flat[b*(NSEG*SEGS) + g*SEGS + pos] = g*SEGF + i;
      pos++;
    }
  }
}

// ---------------- gather selected rows of x, cast to bf16 ----------------
__global__ __launch_bounds__(256) void gather_cast(
    const float* __restrict__ x, const int* __restrict__ flat,
    short* __restrict__ xsel)
{
  int tok  = blockIdx.x * 4 + (threadIdx.x >> 6);
  int lane = threadIdx.x & 63;
  int b = tok >> 10, i = tok & 1023;
  int gidx = flat[b * (NSEG*SEGS) + i];
  const float* srcp = x + ((size_t)(b * S_TOT + gidx)) * DIN + lane*8;
  float4 a0 = *(const float4*)srcp;
  float4 a1 = *(const float4*)(srcp + 4);
  uint4 o;
  o.x = (u32)(unsigned short)f2b(a0.x) | ((u32)(unsigned short)f2b(a0.y) << 16);
  o.y = (u32)(unsigned short)f2b(a0.z) | ((u32)(unsigned short)f2b(a0.w) << 16);
  o.z = (u32)(unsigned short)f2b(a1.x) | ((u32)(unsigned short)f2b(a1.y) << 16);
  o.w = (u32)(unsigned short)f2b(a1.z) | ((u32)(unsigned short)f2b(a1.w) << 16);
  *(uint4*)(xsel + (size_t)tok * DIN + lane*8) = o;
}

// ---------------- bf16 MFMA GEMM, 2-phase pipeline, templated BK --------------
template<int BM, int BN, int WM, int WN, int BK>
__global__ __launch_bounds__(256) void gemm_bf16(
    const short* __restrict__ A, const short* __restrict__ Bt,
    const float* __restrict__ bias, float* __restrict__ Cf,
    short* __restrict__ Cb, short* __restrict__ VtOut, short* __restrict__ KtOut,
    int M, int N, int K, int act)
{
  constexpr int WAVES_N = BN / WN;
  constexpr int FM = WM / 16, FN = WN / 16;
  constexpr int RPB = BK / 8;
  __shared__ short Al[2][BM * BK];
  __shared__ short Bl[2][BN * BK];
  const int tid = threadIdx.x;
  const int lane = tid & 63, wid = tid >> 6;
  const int wr = wid / WAVES_N, wc = wid % WAVES_N;
  const int bm = blockIdx.y * BM, bn = blockIdx.x * BN;
  const int ln15 = lane & 15, hi8 = (lane >> 4) * 8;

  f32x4 acc[FM][FN];
  #pragma unroll
  for (int i = 0; i < FM; ++i)
    #pragma unroll
    for (int j = 0; j < FN; ++j)
      #pragma unroll
      for (int e = 0; e < 4; ++e) acc[i][j][e] = 0.f;

  const int NT = K / BK;

  auto stage = [&](int t, int buf) {
    const int k0 = t * BK;
    #pragma unroll
    for (int i = 0; i < BM*BK/2048; ++i) {
      int slot = i*256 + tid;
      int row = slot / RPB, col = (slot % RPB) * 8;
      const short* gp = A + (size_t)(bm + row) * K + k0 + col;
      __builtin_amdgcn_global_load_lds(
          (const __attribute__((address_space(1))) void*)gp,
          (__attribute__((address_space(3))) void*)&Al[buf][row*BK + col],
          16, 0, 0);
    }
    #pragma unroll
    for (int i = 0; i < BN*BK/2048; ++i) {
      int slot = i*256 + tid;
      int row = slot / RPB, col = (slot % RPB) * 8;
      const short* gp = Bt + (size_t)(bn + row) * K + k0 + col;
      __builtin_amdgcn_global_load_lds(
          (const __attribute__((address_space(1))) void*)gp,
          (__attribute__((address_space(3))) void*)&Bl[buf][row*BK + col],
          16, 0, 0);
    }
  };

  stage(0, 0);
  __syncthreads();
  int cur = 0;
  for (int t = 0; t < NT; ++t) {
    if (t + 1 < NT) stage(t + 1, cur ^ 1);
    #pragma unroll
    for (int ks = 0; ks < BK/32; ++ks) {
      short8 af[FM], bf_[FN];
      #pragma unroll
      for (int fm = 0; fm < FM; ++fm)
        af[fm] = *(const short8*)&Al[cur][(wr*WM + fm*16 + ln15)*BK + ks*32 + hi8];
      #pragma unroll
      for (int fn = 0; fn < FN; ++fn)
        bf_[fn] = *(const short8*)&Bl[cur][(wc*WN + fn*16 + ln15)*BK + ks*32 + hi8];
      #pragma unroll
      for (int fm = 0; fm < FM; ++fm)
        #pragma unroll
        for (int fn = 0; fn < FN; ++fn)
          acc[fm][fn] = __builtin_amdgcn_mfma_f32_16x16x32_bf16(af[fm], bf_[fn], acc[fm][fn], 0, 0, 0);
    }
    __syncthreads();
    cur ^= 1;
  }

  const int crow0 = (lane >> 4) * 4, ccol = lane & 15;
  #pragma unroll
  for (int fm = 0; fm < FM; ++fm) {
    #pragma unroll
    for (int fn = 0; fn < FN; ++fn) {
      int c = bn + wc*WN + fn*16 + ccol;
      int r0 = bm + wr*WM + fm*16 + crow0;
      float vv[4];
      #pragma unroll
      for (int j = 0; j < 4; ++j) {
        float v = acc[fm][fn][j];
        if (bias) v += bias[c];
        if (act == 1) v = 0.5f * v * (1.0f + erff(v * 0.70710678118f));
        vv[j] = v;
        if (Cf) Cf[(size_t)(r0 + j) * N + c] = v;
        if (Cb) Cb[(size_t)(r0 + j) * N + c] = f2b(v);
      }
      if (VtOut && c >= 1024) {
        int hh = (c - 1024) >> 6, dv = c & 63;
        int bb = r0 >> 10, key = r0 & 1023;
        u32 lo = (u32)(unsigned short)f2b(vv[0]) | ((u32)(unsigned short)f2b(vv[1]) << 16);
        u32 hi = (u32)(unsigned short)f2b(vv[2]) | ((u32)(unsigned short)f2b(vv[3]) << 16);
        *(uint2*)&VtOut[((size_t)((bb*8 + hh)*64 + dv) << 10) + key] = make_uint2(lo, hi);
      }
      if (KtOut && c >= 512 && c < 1024) {
        int hh = (c - 512) >> 6, dk = c & 63;
        int bb = r0 >> 10, key = r0 & 1023;
        float e0 = vv[0] > 0.f ? vv[0] + 1.f : __expf(vv[0]);
        float e1 = vv[1] > 0.f ? vv[1] + 1.f : __expf(vv[1]);
        float e2 = vv[2] > 0.f ? vv[2] + 1.f : __expf(vv[2]);
        float e3 = vv[3] > 0.f ? vv[3] + 1.f : __expf(vv[3]);
        u32 lo = (u32)(unsigned short)f2b(e0) | ((u32)(unsigned short)f2b(e1) << 16);
        u32 hi = (u32)(unsigned short)f2b(e2) | ((u32)(unsigned short)f2b(e3) << 16);
        *(uint2*)&KtOut[((size_t)((bb*8 + hh)*64 + dk) << 10) + key] = make_uint2(lo, hi);
      }
    }
  }
}

// ---------------- memsum via MFMA: M0t[b][h][dv][dk] = Vt(seg0) @ Kt(seg0)^T ------
__global__ __launch_bounds__(256) void memsum_mfma(
    const short* __restrict__ Kt, const short* __restrict__ Vt,
    short* __restrict__ m0t, float* __restrict__ zf)
{
  int b = blockIdx.x >> 3, h = blockIdx.x & 7;
  const short* ktb = Kt + ((size_t)((b*8+h)*64) << 10);
  const short* vtb = Vt + ((size_t)((b*8+h)*64) << 10);
  int tid = threadIdx.x, lane = tid & 63, w = tid >> 6;
  int ln15 = lane & 15, hi8 = (lane >> 4) * 8;
  f32x4 acc[4];
  #pragma unroll
  for (int nf = 0; nf < 4; ++nf) acc[nf] = (f32x4){0.f,0.f,0.f,0.f};
  #pragma unroll 4
  for (int ks = 0; ks < 16; ++ks) {
    short8 a = *(const short8*)&vtb[(size_t)(w*16 + ln15)*1024 + ks*32 + hi8];
    #pragma unroll
    for (int nf = 0; nf < 4; ++nf) {
      short8 bfr = *(const short8*)&ktb[(size_t)(nf*16 + ln15)*1024 + ks*32 + hi8];
      acc[nf] = __builtin_amdgcn_mfma_f32_16x16x32_bf16(a, bfr, acc[nf], 0, 0, 0);
    }
  }
  size_t mb = (size_t)(b*NH + h) * 4096;
  #pragma unroll
  for (int nf = 0; nf < 4; ++nf)
    #pragma unroll
    for (int j = 0; j < 4; ++j)
      m0t[mb + (size_t)(w*16 + (lane>>4)*4 + j)*64 + nf*16 + ln15] = f2b(acc[nf][j]);
  int row = tid >> 2, q = tid & 3;
  float zs = 0.f;
  #pragma unroll 4
  for (int i = 0; i < 16; ++i) {
    short8 kv = *(const short8*)&ktb[(size_t)row*1024 + q*128 + i*8];
    #pragma unroll
    for (int e = 0; e < 8; ++e) zs += b2f(kv[e]);
  }
  zs += __shfl_xor(zs, 1); zs += __shfl_xor(zs, 2);
  if (q == 0) zf[(b*8+h)*64 + row] = 0.015625f + zs;
}

// ---------------- fused MFMA attention; XCD-aware decode (h in low bits) ----------
__global__ __launch_bounds__(256) void attn4(
    const short* __restrict__ qkv, const short* __restrict__ vt,
    const short* __restrict__ m0t, const float* __restrict__ zf,
    const float* __restrict__ betas, short* __restrict__ att)
{
  __shared__ short Ks[128*64];      // [key][dk]; reused for Mt
  __shared__ short Vts[64*128];     // [dv][key]
  __shared__ short Ps[4*16*128];    // per-wave P
  __shared__ float zl[64];
  __shared__ float relay[64];
  int tid = threadIdx.x, lane = tid & 63, w = tid >> 6;
  int ln15 = lane & 15, hi8 = (lane >> 4) * 8;
  int bx = blockIdx.x;
  // XCD-aware: blocks sharing K/V (same h,g,b; qt 0..7) are congruent mod 8
  int h = bx & 7, g = (bx >> 3) & 1, b = (bx >> 4) & 3, qt = bx >> 6;
  const int seg0 = b*1024 + g*512;
  const int qbase = seg0 + qt*64;

  short8 qf[2];
  {
    const short* qg = qkv + (size_t)(qbase + w*16 + ln15)*1536 + h*64;
    qf[0] = *(const short8*)(qg + hi8);
    qf[1] = *(const short8*)(qg + 32 + hi8);
  }
  if (g && tid < 16) *(float4*)&zl[tid*4] = *(const float4*)(zf + (size_t)(b*8+h)*64 + tid*4);

  const short* kg = qkv + (size_t)seg0*1536 + 512 + h*64;
  const short* vg = vt + ((size_t)((b*8+h)*64) << 10) + g*512;
  short* Pw = &Ps[w*2048];

  f32x4 oacc[4];
  #pragma unroll
  for (int nf = 0; nf < 4; ++nf) oacc[nf] = (f32x4){0.f,0.f,0.f,0.f};
  float lsum[4] = {0.f,0.f,0.f,0.f};

  for (int c = 0; c < 4; ++c) {
    __syncthreads();
    #pragma unroll
    for (int p = 0; p < 4; ++p) {
      int slot = p*256 + tid;
      int row = slot >> 3;
      int off = ((slot & 7)*8) ^ ((row & 7)*8);
      __builtin_amdgcn_global_load_lds(
        (const __attribute__((address_space(1))) void*)(kg + (size_t)(c*128 + row)*1536 + off),
        (__attribute__((address_space(3))) void*)&Ks[slot*8], 16, 0, 0);
    }
    #pragma unroll
    for (int p = 0; p < 4; ++p) {
      int slot = p*256 + tid;
      int row = slot >> 4;
      int off = ((slot & 15)*8) ^ ((row & 7)*8);
      __builtin_amdgcn_global_load_lds(
        (const __attribute__((address_space(1))) void*)(vg + ((size_t)row << 10) + c*128 + off),
        (__attribute__((address_space(3))) void*)&Vts[slot*8], 16, 0, 0);
    }
    __syncthreads();

    f32x4 sf[8];
    #pragma unroll
    for (int nf = 0; nf < 8; ++nf) sf[nf] = (f32x4){0.f,0.f,0.f,0.f};
    __builtin_amdgcn_s_setprio(1);
    #pragma unroll
    for (int ks = 0; ks < 2; ++ks)
      #pragma unroll
      for (int nf = 0; nf < 8; ++nf) {
        int row = nf*16 + ln15;
        short8 kb = *(const short8*)&Ks[row*64 + ((ks*32 + hi8) ^ ((row&7)*8))];
        sf[nf] = __builtin_amdgcn_mfma_f32_16x16x32_bf16(qf[ks], kb, sf[nf], 0, 0, 0);
      }
    __builtin_amdgcn_s_setprio(0);
    #pragma unroll
    for (int nf = 0; nf < 8; ++nf)
      #pragma unroll
      for (int j = 0; j < 4; ++j) {
        float p = __expf(sf[nf][j] * 0.125f);
        lsum[j] += p;
        int q = (lane >> 4)*4 + j;
        int key = nf*16 + ln15;
        Pw[q*128 + (key ^ ((q&7)*8))] = f2b(p);
      }
    __builtin_amdgcn_s_setprio(1);
    #pragma unroll
    for (int ks = 0; ks < 4; ++ks) {
      short8 pa = *(const short8*)&Pw[ln15*128 + ((ks*32 + hi8) ^ ((ln15&7)*8))];
      #pragma unroll
      for (int nf = 0; nf < 4; ++nf) {
        int row = nf*16 + ln15;
        short8 vb = *(const short8*)&Vts[row*128 + ((ks*32 + hi8) ^ ((row&7)*8))];
        oacc[nf] = __builtin_amdgcn_mfma_f32_16x16x32_bf16(pa, vb, oacc[nf], 0, 0, 0);
      }
    }
    __builtin_amdgcn_s_setprio(0);
  }

  float linv[4];
  #pragma unroll
  for (int j = 0; j < 4; ++j) {
    float s = lsum[j];
    s += __shfl_xor(s, 1); s += __shfl_xor(s, 2);
    s += __shfl_xor(s, 4); s += __shfl_xor(s, 8);
    linv[j] = 1.f / s;
  }

  f32x4 mfr[4];
  #pragma unroll
  for (int nf = 0; nf < 4; ++nf) mfr[nf] = (f32x4){0.f,0.f,0.f,0.f};
  float dinv[4] = {0.f,0.f,0.f,0.f};
  if (g) {
    __syncthreads();
    const short* mg = m0t + (size_t)(b*8+h)*4096;
    #pragma unroll
    for (int p = 0; p < 2; ++p) {
      int slot = p*256 + tid;
      int row = slot >> 3;
      int off = ((slot & 7)*8) ^ ((row & 7)*8);
      __builtin_amdgcn_global_load_lds(
        (const __attribute__((address_space(1))) void*)(mg + (size_t)row*64 + off),
        (__attribute__((address_space(3))) void*)&Ks[slot*8], 16, 0, 0);
    }
    __syncthreads();
    float sqv[2][8]; short8 sqf[2];
    #pragma unroll
    for (int ks = 0; ks < 2; ++ks)
      #pragma unroll
      for (int e = 0; e < 8; ++e) {
        float f = b2f(qf[ks][e]);
        f = f > 0.f ? f + 1.f : __expf(f);
        sqv[ks][e] = f; sqf[ks][e] = f2b(f);
      }
    float denp = 0.f;
    #pragma unroll
    for (int ks = 0; ks < 2; ++ks)
      #pragma unroll
      for (int e = 0; e < 8; ++e) denp += sqv[ks][e] * zl[ks*32 + hi8 + e];
    denp += __shfl_xor(denp, 16); denp += __shfl_xor(denp, 32);
    if (lane < 16) relay[w*16 + lane] = denp;
    #pragma unroll
    for (int ks = 0; ks < 2; ++ks)
      #pragma unroll
      for (int nf = 0; nf < 4; ++nf) {
        int row = nf*16 + ln15;
        short8 mb_ = *(const short8*)&Ks[row*64 + ((ks*32 + hi8) ^ ((row&7)*8))];
        mfr[nf] = __builtin_amdgcn_mfma_f32_16x16x32_bf16(sqf[ks], mb_, mfr[nf], 0, 0, 0);
      }
    #pragma unroll
    for (int j = 0; j < 4; ++j)
      dinv[j] = 1.f / relay[w*16 + (lane>>4)*4 + j];
  }

  #pragma unroll
  for (int nf = 0; nf < 4; ++nf) {
    float bt = betas[h*64 + nf*16 + ln15];
    float gt = 1.f / (1.f + __expf(-bt));
    #pragma unroll
    for (int j = 0; j < 4; ++j) {
      float ad = oacc[nf][j] * linv[j];
      float v = g ? (gt * mfr[nf][j] * dinv[j] + (1.f - gt) * ad) : (1.f - gt) * ad;
      int qrow = qbase + w*16 + (lane>>4)*4 + j;
      att[(size_t)qrow*512 + h*64 + nf*16 + ln15] = f2b(v);
    }
  }
}

// ---------------- final: x_out = (x + scatter(h)) * pad ----------------
__global__ __launch_bounds__(256) void final_kernel(
    const float* __restrict__ x, const int* __restrict__ inv,
    const float* __restrict__ hm, float* __restrict__ outX)
{
  int row  = blockIdx.x * 4 + (threadIdx.x >> 6);
  int lane = threadIdx.x & 63;
  int b = row >> 14;
  int s = row & (S_TOT - 1);
  size_t base = (size_t)row * DIN + lane * 8;
  if (s >= NUSE * SEGF) {
    float4 z = make_float4(0.f,0.f,0.f,0.f);
    *(float4*)(outX + base)     = z;
    *(float4*)(outX + base + 4) = z;
    return;
  }
  float4 a0 = *(const float4*)(x + base);
  float4 a1 = *(const float4*)(x + base + 4);
  int i = inv[b * (NUSE*SEGF) + s];
  if (i >= 0) {
    size_t hb = (size_t)(b * (NUSE*SEGS) + i) * DIN + lane * 8;
    float4 h0 = *(const float4*)(hm + hb);
    float4 h1 = *(const float4*)(hm + hb + 4);
    a0.x += h0.x; a0.y += h0.y; a0.z += h0.z; a0.w += h0.w;
    a1.x += h1.x; a1.y += h1.y; a1.z += h1.z; a1.w += h1.w;
  }
  *(float4*)(outX + base)     = a0;
  *(float4*)(outX + base + 4) = a1;
}

extern "C" void kernel_launch(void* const* d_in, const int* in_sizes, int n_in,
                              void* d_out, int out_size, void* d_ws, size_t ws_size,
                              hipStream_t stream) {
  (void)in_sizes; (void)n_in; (void)out_size; (void)ws_size;
  const float* x      = (const float*)d_in[0];
  const float* w_samp = (const float*)d_in[1];
  const float* b_samp = (const float*)d_in[2];
  const float* w_q    = (const float*)d_in[3];
  const float* w_k    = (const float*)d_in[4];
  const float* w_v    = (const float*)d_in[5];
  const float* w_o    = (const float*)d_in[6];
  const float* betas  = (const float*)d_in[7];
  const float* w1     = (const float*)d_in[8];
  const float* b1     = (const float*)d_in[9];
  const float* w2     = (const float*)d_in[10];
  const float* b2     = (const float*)d_in[11];

  float* outX      = (float*)d_out;
  float* outMask   = outX + (size_t)BATCH * S_TOT * DIN;
  float* outScores = outMask + (size_t)BATCH * S_TOT;

  char* ws = (char*)d_ws;
  int*   flat  = (int*)(ws);                    // 64 KB
  int*   inv   = (int*)(ws + 65536);            // 64 KB
  int*   flags = (int*)(ws + 131072);           // 256 KB
  short* M0t   = (short*)(ws + 393216);         // [32][64][64] bf16, 256 KB
  float* Zf    = (float*)(ws + 655360);         // [32][64] f32, 8 KB
  short* Wtqkv = (short*)(ws + 1048576);        // [1536][512] bf16, 1.5 MB
  short* Wob   = (short*)(ws + 2621440);        // [512][512] plain cast, 0.5 MB
  short* Wt1   = (short*)(ws + 3145728);        // [2048][512], 2 MB
  short* Wt2   = (short*)(ws + 5242880);        // [512][2048], 2 MB
  short* xsel  = (short*)(ws + 7340032);        // [4096][512], 4 MB
  short* qkv   = (short*)(ws + 11534336);       // [4096][1536], 12 MB
  short* Vt    = (short*)(ws + 24117248);       // [4][8][64][1024], 4 MB
  short* attb  = (short*)(ws + 28311552);       // [4096][512], 4 MB
  short* Kt    = (short*)(ws + 36700160);       // [4][8][64][1024], 4 MB
  short* WfT   = (short*)(ws + 40894464);       // [2048][512] = (w_o@w1)^T, 2 MB
  short* hidB  = (short*)(ws + 7340032);        // [4096][2048] overlays xsel+qkv
  float* Hf    = (float*)(ws + 24117248);       // [4096][512] f32 overlays Vt+attb

  scores_transpose<<<16384 + 3072, 256, 0, stream>>>(
      x, w_samp, b_samp, outScores,
      w_q, w_k, w_v, w_o, w1, w2, Wtqkv, Wob, Wt1, Wt2);
  topk_rank<<<BATCH*NSEG*8, 1024, 0, stream>>>(outScores, flags, outMask);
  topk_compact<<<BATCH*NUSE, 256, 0, stream>>>(flags, flat, inv);

  gemm_bf16<64,64,32,32,64><<<dim3(8,32), 256, 0, stream>>>(
      Wt1, Wob, nullptr, nullptr, WfT, nullptr, nullptr, 2048, 512, 512, 0);

  gather_cast<<<MROWS/4, 256, 0, stream>>>(x, flat, xsel);

  gemm_bf16<128,128,64,64,32><<<dim3(12,32), 256, 0, stream>>>(
      xsel, Wtqkv, nullptr, nullptr, qkv, Vt, Kt, MROWS, 1536, 512, 0);

  memsum_mfma<<<BATCH*NH, 256, 0, stream>>>(Kt, Vt, M0t, Zf);
  attn4<<<512, 256, 0, stream>>>(qkv, Vt, M0t, Zf, betas, attb);

  gemm_bf16<128,128,64,64,32><<<dim3(16,32), 256, 0, stream>>>(
      attb, WfT, b1, nullptr, hidB, nullptr, nullptr, MROWS, 2048, 512, 1);
  gemm_bf16<64,64,32,32,64><<<dim3(8,64), 256, 0, stream>>>(
      hidB, Wt2, b2, Hf, nullptr, nullptr, nullptr, MROWS, 512, 2048, 0);

  final_kernel<<<(BATCH*S_TOT)/4, 256, 0, stream>>>(x, inv, Hf, outX);
}